// Round 5
// baseline (77.587 us; speedup 1.0000x reference)
//
#include <hip/hip_runtime.h>
#include <cstdint>
#include <cstddef>

// GAT layer: B=4, H=8, N=2048, Din=256, O=64
// out[b,h,i,o] = sum_j softmax_j(leaky_relu(src[i]+dst[j])) * h_[b,h,j,o] + bias[o]
//
// Tricks:
//  - row max of logits = leaky(src_i + max_j dst_j) exactly (monotonicity) -> no
//    online rescaling; p <= 1 always. src/dst pre-scaled by log2e -> raw v_exp_f32.
//  - p row-sums via MFMA against an all-ones B fragment -> same lane/reg slot as
//    the PV accumulator row -> shuffle-free normalization.
//  - V stored FRAGMENT-MAJOR: v2[bh][j>>3][o][j&7] -> B-frag load = 4 contiguous
//    256B runs. Explicit 2-deep register double-buffer in flash.
//  - h converted to bf16 ONCE (stored in front of d_out, rewritten later by flash).
//  - R4 bisection: p-path reverted to R2's known-good scalar fmaxf/exp2/pkbf
//    (R3's v_cvt_pk_bf16_f32 asm + packed-f32 path is the prime suspect).

#define HEADS 8
#define DIN   256
#define HDIM  64
#define NN    2048

typedef __attribute__((ext_vector_type(8))) short bf16x8;
typedef __attribute__((ext_vector_type(4))) float f32x4;

union BF8 { bf16x8 v; unsigned u[4]; };

__device__ __forceinline__ unsigned pkbf(float a, float b) {
  // returns (bf16(b)<<16) | bf16(a), round-half-up
  union { float f; unsigned u; } ua, ub; ua.f = a; ub.f = b;
  return __builtin_amdgcn_perm(ub.u + 0x8000u, ua.u + 0x8000u, 0x07060302u);
}

__device__ __forceinline__ unsigned short f2bf(float f) {
  union { float f; unsigned u; } v; v.f = f;
  unsigned r = v.u + 0x7FFFu + ((v.u >> 16) & 1u);   // RNE
  return (unsigned short)(r >> 16);
}

// ---------------- k0a: w [H][K][O] f32 -> wt [H][O][K] bf16 ---------------
__global__ __launch_bounds__(256) void gat_wt(const float* __restrict__ w,
                                              unsigned short* __restrict__ wt) {
  const int idx = blockIdx.x * 256 + threadIdx.x;   // over 8*256*64 = 131072
  const int o  = idx & 63;
  const int k  = (idx >> 6) & 255;
  const int hd = idx >> 14;
  wt[(hd * HDIM + o) * DIN + k] = f2bf(w[idx]);
}

// ---------------- k0b: h f32 -> bf16 (once, not 8x per head) --------------
__global__ __launch_bounds__(256) void gat_hc(const float* __restrict__ h,
                                              unsigned short* __restrict__ hc) {
  const int idx = blockIdx.x * 256 + threadIdx.x;   // 262144 threads x 8 elems
  const float* p = h + (size_t)idx * 8;
  float4 x0 = ((const float4*)p)[0];
  float4 x1 = ((const float4*)p)[1];
  uint4 o;
  o.x = pkbf(x0.x, x0.y); o.y = pkbf(x0.z, x0.w);
  o.z = pkbf(x1.x, x1.y); o.w = pkbf(x1.z, x1.w);
  *(uint4*)(hc + (size_t)idx * 8) = o;
}

// ---------------- k1: projection + fused src/dst logit vectors ------------
// grid (HEADS, 64): head = bx, 128-row tile of B*N=8192 = by
// writes V fragment-major: h_t[bh][g = j>>3][o][j&7]  (g stride 512 elems)
__global__ __launch_bounds__(256) void gat_proj(const unsigned short* __restrict__ hc,
                                                const unsigned short* __restrict__ wt,
                                                const float* __restrict__ a_src,
                                                const float* __restrict__ a_dst,
                                                unsigned short* __restrict__ h_t,
                                                float* __restrict__ src_s,
                                                float* __restrict__ dst_s) {
  const int head = blockIdx.x;
  const int rt   = blockIdx.y;
  const int tid  = threadIdx.x;
  const int w    = tid >> 6;
  const int lane = tid & 63;
  const int l15  = lane & 15, lg = lane >> 4;

  const int rowg = rt * 128 + w * 32;                 // global row in [0,8192)
  const unsigned short* hb = hc + (size_t)rowg * DIN;
  const unsigned short* wb = wt + head * (HDIM * DIN);

  f32x4 acc[2][4] = {};
#pragma unroll
  for (int kk = 0; kk < 8; ++kk) {
    const int k0 = kk * 32 + lg * 8;
    bf16x8 af[2];
#pragma unroll
    for (int m = 0; m < 2; ++m)
      af[m] = *(const bf16x8*)(hb + (size_t)(m * 16 + l15) * DIN + k0);
    bf16x8 bfr[4];
#pragma unroll
    for (int n = 0; n < 4; ++n)
      bfr[n] = *(const bf16x8*)(wb + (size_t)(n * 16 + l15) * DIN + k0);
#pragma unroll
    for (int m = 0; m < 2; ++m)
#pragma unroll
      for (int n = 0; n < 4; ++n)
        acc[m][n] = __builtin_amdgcn_mfma_f32_16x16x32_bf16(af[m], bfr[n], acc[m][n], 0, 0, 0);
  }

  // fragment-major store: C regs are 4 consecutive rows(j), same col(o)
  const int b   = (rt * 128) >> 11;
  const int nl0 = ((rt * 128) & 2047) + w * 32;       // node index within batch b
  const int bh  = b * HEADS + head;
  unsigned short* hb_t = h_t + (size_t)bh * (256 * 512);
#pragma unroll
  for (int m = 0; m < 2; ++m)
#pragma unroll
    for (int n = 0; n < 4; ++n) {
      uint2 pk;
      pk.x = pkbf(acc[m][n][0], acc[m][n][1]);
      pk.y = pkbf(acc[m][n][2], acc[m][n][3]);
      const int j0 = nl0 + m * 16 + lg * 4;           // 4 consecutive j
      const int o  = n * 16 + l15;
      *(uint2*)(hb_t + (size_t)(j0 >> 3) * 512 + o * 8 + (j0 & 7)) = pk;
    }

  // fused src/dst: src[node] = sum_o h_[node][o]*a_src[o]  (f32 acc, pre-scaled)
  const float LOG2E = 1.4426950408889634f;
  float as4[4], ad4[4];
#pragma unroll
  for (int n = 0; n < 4; ++n) {
    as4[n] = a_src[head * HDIM + n * 16 + l15];
    ad4[n] = a_dst[head * HDIM + n * 16 + l15];
  }
#pragma unroll
  for (int m = 0; m < 2; ++m)
#pragma unroll
    for (int reg = 0; reg < 4; ++reg) {
      float ps = 0.f, pd = 0.f;
#pragma unroll
      for (int n = 0; n < 4; ++n) {
        float c = acc[m][n][reg];
        ps = fmaf(c, as4[n], ps);
        pd = fmaf(c, ad4[n], pd);
      }
#pragma unroll
      for (int off = 1; off <= 8; off <<= 1) {
        ps += __shfl_xor(ps, off);
        pd += __shfl_xor(pd, off);
      }
      if (l15 == 0) {
        const int nl = nl0 + m * 16 + lg * 4 + reg;
        src_s[(size_t)bh * NN + nl] = ps * LOG2E;
        dst_s[(size_t)bh * NN + nl] = pd * LOG2E;
      }
    }
}

// ---------------- k2: flash GAT attention ---------------------------------
// grid (32, 32): i-tile(64 rows) = bx, bh = by; 4 waves x 16 rows (m=1)
__global__ __launch_bounds__(256, 4) void gat_flash(const float* __restrict__ src_s,
                                                    const float* __restrict__ dst_s,
                                                    const unsigned short* __restrict__ h_t,
                                                    const float* __restrict__ bias,
                                                    float* __restrict__ out) {
  const int it  = blockIdx.x;
  const int bh  = blockIdx.y;
  const int tid = threadIdx.x;
  const int w   = tid >> 6;
  const int lane = tid & 63;
  const int l15 = lane & 15, lg = lane >> 4;

  const float* dstp = dst_s + (size_t)bh * NN;

  // exact global max of dst for this (b,h)
  float dm = -1e30f;
#pragma unroll
  for (int t = 0; t < NN / 256; ++t) dm = fmaxf(dm, dstp[tid + t * 256]);
#pragma unroll
  for (int off = 32; off >= 1; off >>= 1) dm = fmaxf(dm, __shfl_xor(dm, off));
  __shared__ float red[4];
  if (lane == 0) red[w] = dm;
  __syncthreads();
  dm = fmaxf(fmaxf(red[0], red[1]), fmaxf(red[2], red[3]));

  // this lane's A-frag row = l15 of the wave's 16-row tile
  const float sv   = src_s[(size_t)bh * NN + it * 64 + w * 16 + l15];
  const float smax = sv + dm;
  const float mi   = fmaxf(smax, 0.2f * smax);   // exact row max (log2 domain)
  const float sm0  = sv - mi;                    // pos branch:  p2 = sm0 + d
  const float c0   = fmaf(0.2f, sv, -mi);        // neg branch:  p2 = 0.2*d + c0

  f32x4 acc[4] = {};
  f32x4 accs   = {};
  BF8 onesU; onesU.u[0] = onesU.u[1] = onesU.u[2] = onesU.u[3] = 0x3F803F80u;
  const bf16x8 ones = onesU.v;

  // fragment-major base for this lane: group (jc*4+lg), col (n*16+l15)
  const unsigned short* fb = h_t + (size_t)bh * (256 * 512) + lg * 512 + l15 * 8;

#define LOADF(P, jc) do {                                              \
    const unsigned short* fp_ = fb + (size_t)(jc) * 2048;              \
    P##0 = *(const bf16x8*)(fp_);                                      \
    P##1 = *(const bf16x8*)(fp_ + 128);                                \
    P##2 = *(const bf16x8*)(fp_ + 256);                                \
    P##3 = *(const bf16x8*)(fp_ + 384);                                \
    P##d0 = *(const float4*)(dstp + (jc) * 32 + lg * 8);               \
    P##d1 = *(const float4*)(dstp + (jc) * 32 + lg * 8 + 4);           \
  } while (0)

#define FLASH_STEP(B0_, B1_, B2_, B3_, D0_, D1_) do {                  \
    const float dv_[8] = {D0_.x, D0_.y, D0_.z, D0_.w,                  \
                          D1_.x, D1_.y, D1_.z, D1_.w};                 \
    float p_[8];                                                       \
    _Pragma("unroll") for (int jj = 0; jj < 8; ++jj)                   \
      p_[jj] = __builtin_amdgcn_exp2f(                                 \
          fmaxf(sm0 + dv_[jj], fmaf(0.2f, dv_[jj], c0)));              \
    BF8 afu_;                                                          \
    afu_.u[0] = pkbf(p_[0], p_[1]); afu_.u[1] = pkbf(p_[2], p_[3]);    \
    afu_.u[2] = pkbf(p_[4], p_[5]); afu_.u[3] = pkbf(p_[6], p_[7]);    \
    acc[0] = __builtin_amdgcn_mfma_f32_16x16x32_bf16(afu_.v, B0_, acc[0], 0, 0, 0); \
    acc[1] = __builtin_amdgcn_mfma_f32_16x16x32_bf16(afu_.v, B1_, acc[1], 0, 0, 0); \
    acc[2] = __builtin_amdgcn_mfma_f32_16x16x32_bf16(afu_.v, B2_, acc[2], 0, 0, 0); \
    acc[3] = __builtin_amdgcn_mfma_f32_16x16x32_bf16(afu_.v, B3_, acc[3], 0, 0, 0); \
    accs   = __builtin_amdgcn_mfma_f32_16x16x32_bf16(afu_.v, ones, accs, 0, 0, 0);  \
  } while (0)

  bf16x8 A0, A1, A2, A3, B0, B1, B2, B3;
  float4 Ad0, Ad1, Bd0, Bd1;

  LOADF(A, 0);
#pragma unroll 1
  for (int jc2 = 0; jc2 < 31; ++jc2) {
    LOADF(B, 2 * jc2 + 1);
    FLASH_STEP(A0, A1, A2, A3, Ad0, Ad1);
    LOADF(A, 2 * jc2 + 2);
    FLASH_STEP(B0, B1, B2, B3, Bd0, Bd1);
  }
  LOADF(B, 63);
  FLASH_STEP(A0, A1, A2, A3, Ad0, Ad1);
  FLASH_STEP(B0, B1, B2, B3, Bd0, Bd1);

#undef LOADF
#undef FLASH_STEP

  float bb[4];
#pragma unroll
  for (int n = 0; n < 4; ++n) bb[n] = bias[n * 16 + l15];

  float* ob = out + ((size_t)bh * NN + it * 64 + w * 16) * HDIM;
#pragma unroll
  for (int reg = 0; reg < 4; ++reg) {
    const float linv = 1.0f / accs[reg];   // rowsum, same lane & reg as acc
    const int r = lg * 4 + reg;
#pragma unroll
    for (int n = 0; n < 4; ++n)
      ob[(size_t)r * HDIM + n * 16 + l15] = fmaf(acc[n][reg], linv, bb[n]);
  }
}

extern "C" void kernel_launch(void* const* d_in, const int* in_sizes, int n_in,
                              void* d_out, int out_size, void* d_ws, size_t ws_size,
                              hipStream_t stream) {
  const float* h     = (const float*)d_in[0];   // [4,2048,256]
  const float* w     = (const float*)d_in[1];   // [8,256,64]
  const float* a_src = (const float*)d_in[2];   // [8,64,1]
  const float* a_dst = (const float*)d_in[3];   // [8,64,1]
  const float* bias  = (const float*)d_in[4];   // [64]
  float* out = (float*)d_out;                   // [4,8,2048,64]

  // ws layout (~8.75 MB)
  char* ws = (char*)d_ws;
  unsigned short* wt  = (unsigned short*)ws;                       // 256 KB
  unsigned short* h_t = (unsigned short*)(ws + 262144);            // 8 MB (V frag-major)
  float* src_s = (float*)(ws + 262144 + 8388608);                  // 256 KB
  float* dst_s = (float*)(ws + 262144 + 8388608 + 262144);         // 256 KB

  // bf16 copy of h lives in the FRONT of d_out (4 MB of 16 MB): written by
  // gat_hc, read only by gat_proj, then d_out is fully rewritten by gat_flash.
  unsigned short* hcv = (unsigned short*)d_out;

  hipLaunchKernelGGL(gat_wt,    dim3(512),    dim3(256), 0, stream, w, wt);
  hipLaunchKernelGGL(gat_hc,    dim3(1024),   dim3(256), 0, stream, h, hcv);
  hipLaunchKernelGGL(gat_proj,  dim3(8, 64),  dim3(256), 0, stream,
                     hcv, wt, a_src, a_dst, h_t, src_s, dst_s);
  hipLaunchKernelGGL(gat_flash, dim3(32, 32), dim3(256), 0, stream,
                     src_s, dst_s, h_t, bias, out);
}

// Round 6
// 77.397 us; speedup vs baseline: 1.0025x; 1.0025x over previous
//
#include <hip/hip_runtime.h>
#include <cstdint>
#include <cstddef>

// GAT layer: B=4, H=8, N=2048, Din=256, O=64
// out[b,h,i,o] = sum_j softmax_j(leaky_relu(src[i]+dst[j])) * h_[b,h,j,o] + bias[o]
//
// Tricks:
//  - row max of logits = leaky(src_i + max_j dst_j) exactly (monotonicity) -> no
//    online rescaling; p <= 1 always. src/dst pre-scaled by log2e -> raw v_exp_f32.
//  - p row-sums via MFMA against an all-ones B fragment -> same lane/reg slot as
//    the PV accumulator row -> shuffle-free normalization.
//  - V stored FRAGMENT-MAJOR: v2[bh][j>>3][o][j&7] -> B-frag load = 4 contiguous
//    256B runs. Explicit 2-deep register double-buffer in flash.
//  - h converted to bf16 ONCE (stored in front of d_out, rewritten later by flash).
//  - R5: flash back to m=2 (R4 showed m=1 doubles L2 V-traffic: 57.7 vs 47.7 us);
//    logit math in packed f32x2 (v_pk_*), scalar exp2, pkbf pack (NO cvt_pk asm —
//    completes the R3 bisection). proj switched to m=1 grid(8,128) for occupancy.

#define HEADS 8
#define DIN   256
#define HDIM  64
#define NN    2048

typedef __attribute__((ext_vector_type(8))) short bf16x8;
typedef __attribute__((ext_vector_type(4))) float f32x4;
typedef __attribute__((ext_vector_type(2))) float f32x2;

union BF8 { bf16x8 v; unsigned u[4]; };

__device__ __forceinline__ unsigned pkbf(float a, float b) {
  // returns (bf16(b)<<16) | bf16(a), round-half-up
  union { float f; unsigned u; } ua, ub; ua.f = a; ub.f = b;
  return __builtin_amdgcn_perm(ub.u + 0x8000u, ua.u + 0x8000u, 0x07060302u);
}

__device__ __forceinline__ unsigned short f2bf(float f) {
  union { float f; unsigned u; } v; v.f = f;
  unsigned r = v.u + 0x7FFFu + ((v.u >> 16) & 1u);   // RNE
  return (unsigned short)(r >> 16);
}

// ---------------- k0a: w [H][K][O] f32 -> wt [H][O][K] bf16 ---------------
__global__ __launch_bounds__(256) void gat_wt(const float* __restrict__ w,
                                              unsigned short* __restrict__ wt) {
  const int idx = blockIdx.x * 256 + threadIdx.x;   // over 8*256*64 = 131072
  const int o  = idx & 63;
  const int k  = (idx >> 6) & 255;
  const int hd = idx >> 14;
  wt[(hd * HDIM + o) * DIN + k] = f2bf(w[idx]);
}

// ---------------- k0b: h f32 -> bf16 (once, not 8x per head) --------------
__global__ __launch_bounds__(256) void gat_hc(const float* __restrict__ h,
                                              unsigned short* __restrict__ hc) {
  const int idx = blockIdx.x * 256 + threadIdx.x;   // 262144 threads x 8 elems
  const float* p = h + (size_t)idx * 8;
  float4 x0 = ((const float4*)p)[0];
  float4 x1 = ((const float4*)p)[1];
  uint4 o;
  o.x = pkbf(x0.x, x0.y); o.y = pkbf(x0.z, x0.w);
  o.z = pkbf(x1.x, x1.y); o.w = pkbf(x1.z, x1.w);
  *(uint4*)(hc + (size_t)idx * 8) = o;
}

// ---------------- k1: projection + fused src/dst logit vectors ------------
// grid (HEADS, 128): head = bx, 64-row tile of B*N=8192 = by; 4 waves x 16 rows
// writes V fragment-major: h_t[bh][g = j>>3][o][j&7]  (g stride 512 elems)
__global__ __launch_bounds__(256) void gat_proj(const unsigned short* __restrict__ hc,
                                                const unsigned short* __restrict__ wt,
                                                const float* __restrict__ a_src,
                                                const float* __restrict__ a_dst,
                                                unsigned short* __restrict__ h_t,
                                                float* __restrict__ src_s,
                                                float* __restrict__ dst_s) {
  const int head = blockIdx.x;
  const int rt   = blockIdx.y;
  const int tid  = threadIdx.x;
  const int w    = tid >> 6;
  const int lane = tid & 63;
  const int l15  = lane & 15, lg = lane >> 4;

  const int rowg = rt * 64 + w * 16;                  // global row in [0,8192)
  const unsigned short* hb = hc + (size_t)rowg * DIN;
  const unsigned short* wb = wt + head * (HDIM * DIN);

  f32x4 acc[4] = {};
#pragma unroll
  for (int kk = 0; kk < 8; ++kk) {
    const int k0 = kk * 32 + lg * 8;
    bf16x8 af = *(const bf16x8*)(hb + (size_t)l15 * DIN + k0);
    bf16x8 bfr[4];
#pragma unroll
    for (int n = 0; n < 4; ++n)
      bfr[n] = *(const bf16x8*)(wb + (size_t)(n * 16 + l15) * DIN + k0);
#pragma unroll
    for (int n = 0; n < 4; ++n)
      acc[n] = __builtin_amdgcn_mfma_f32_16x16x32_bf16(af, bfr[n], acc[n], 0, 0, 0);
  }

  // fragment-major store: C regs are 4 consecutive rows(j), same col(o)
  const int b   = (rt * 64) >> 11;
  const int nl0 = ((rt * 64) & 2047) + w * 16;        // node index within batch b
  const int bh  = b * HEADS + head;
  unsigned short* hb_t = h_t + (size_t)bh * (256 * 512);
  const int j0 = nl0 + lg * 4;                        // 4 consecutive j
#pragma unroll
  for (int n = 0; n < 4; ++n) {
    uint2 pk;
    pk.x = pkbf(acc[n][0], acc[n][1]);
    pk.y = pkbf(acc[n][2], acc[n][3]);
    const int o = n * 16 + l15;
    *(uint2*)(hb_t + (size_t)(j0 >> 3) * 512 + o * 8 + (j0 & 7)) = pk;
  }

  // fused src/dst: src[node] = sum_o h_[node][o]*a_src[o]  (f32 acc, pre-scaled)
  const float LOG2E = 1.4426950408889634f;
  float as4[4], ad4[4];
#pragma unroll
  for (int n = 0; n < 4; ++n) {
    as4[n] = a_src[head * HDIM + n * 16 + l15];
    ad4[n] = a_dst[head * HDIM + n * 16 + l15];
  }
#pragma unroll
  for (int reg = 0; reg < 4; ++reg) {
    float ps = 0.f, pd = 0.f;
#pragma unroll
    for (int n = 0; n < 4; ++n) {
      float c = acc[n][reg];
      ps = fmaf(c, as4[n], ps);
      pd = fmaf(c, ad4[n], pd);
    }
#pragma unroll
    for (int off = 1; off <= 8; off <<= 1) {
      ps += __shfl_xor(ps, off);
      pd += __shfl_xor(pd, off);
    }
    if (l15 == 0) {
      const int nl = nl0 + lg * 4 + reg;
      src_s[(size_t)bh * NN + nl] = ps * LOG2E;
      dst_s[(size_t)bh * NN + nl] = pd * LOG2E;
    }
  }
}

// ---------------- k2: flash GAT attention ---------------------------------
// grid (16, 32): i-tile(128 rows) = bx, bh = by; 4 waves x 32 rows (2 m-tiles)
__global__ __launch_bounds__(256) void gat_flash(const float* __restrict__ src_s,
                                                 const float* __restrict__ dst_s,
                                                 const unsigned short* __restrict__ h_t,
                                                 const float* __restrict__ bias,
                                                 float* __restrict__ out) {
  const int it  = blockIdx.x;
  const int bh  = blockIdx.y;
  const int tid = threadIdx.x;
  const int w   = tid >> 6;
  const int lane = tid & 63;
  const int l15 = lane & 15, lg = lane >> 4;

  const float* dstp = dst_s + (size_t)bh * NN;

  // exact global max of dst for this (b,h)
  float dm = -1e30f;
#pragma unroll
  for (int t = 0; t < NN / 256; ++t) dm = fmaxf(dm, dstp[tid + t * 256]);
#pragma unroll
  for (int off = 32; off >= 1; off >>= 1) dm = fmaxf(dm, __shfl_xor(dm, off));
  __shared__ float red[4];
  if (lane == 0) red[w] = dm;
  __syncthreads();
  dm = fmaxf(fmaxf(red[0], red[1]), fmaxf(red[2], red[3]));

  // per-lane row state: A-frag row = l15 within each 16-row m-tile
  const float* srcp = src_s + (size_t)bh * NN + it * 128 + w * 32;
  f32x2 sm02[2], c02[2];
#pragma unroll
  for (int m = 0; m < 2; ++m) {
    float sv   = srcp[m * 16 + l15];
    float smax = sv + dm;
    float mi   = fmaxf(smax, 0.2f * smax);   // exact row max (log2 domain)
    float s0   = sv - mi;                    // pos branch:  p2 = s0 + d
    float cc   = fmaf(0.2f, sv, -mi);        // neg branch:  p2 = 0.2*d + cc
    sm02[m] = (f32x2){s0, s0};
    c02[m]  = (f32x2){cc, cc};
  }

  f32x4 acc[2][4] = {};
  f32x4 accs[2]   = {};
  BF8 onesU; onesU.u[0] = onesU.u[1] = onesU.u[2] = onesU.u[3] = 0x3F803F80u;
  const bf16x8 ones = onesU.v;

  // fragment-major base for this lane: group (jc*4+lg), col (n*16+l15)
  const unsigned short* fb = h_t + (size_t)bh * (256 * 512) + lg * 512 + l15 * 8;

#define LOADF(P, jc) do {                                              \
    const unsigned short* fp_ = fb + (size_t)(jc) * 2048;              \
    P##0 = *(const bf16x8*)(fp_);                                      \
    P##1 = *(const bf16x8*)(fp_ + 128);                                \
    P##2 = *(const bf16x8*)(fp_ + 256);                                \
    P##3 = *(const bf16x8*)(fp_ + 384);                                \
    P##d0 = *(const float4*)(dstp + (jc) * 32 + lg * 8);               \
    P##d1 = *(const float4*)(dstp + (jc) * 32 + lg * 8 + 4);           \
  } while (0)

#define FLASH_STEP(B0_, B1_, B2_, B3_, D0_, D1_) do {                  \
    f32x2 e0_ = {D0_.x, D0_.y}, e1_ = {D0_.z, D0_.w};                  \
    f32x2 e2_ = {D1_.x, D1_.y}, e3_ = {D1_.z, D1_.w};                  \
    f32x2 t0_ = e0_ * 0.2f, t1_ = e1_ * 0.2f;                          \
    f32x2 t2_ = e2_ * 0.2f, t3_ = e3_ * 0.2f;                          \
    _Pragma("unroll") for (int m = 0; m < 2; ++m) {                    \
      f32x2 m0_ = __builtin_elementwise_max(e0_ + sm02[m], t0_ + c02[m]); \
      f32x2 m1_ = __builtin_elementwise_max(e1_ + sm02[m], t1_ + c02[m]); \
      f32x2 m2_ = __builtin_elementwise_max(e2_ + sm02[m], t2_ + c02[m]); \
      f32x2 m3_ = __builtin_elementwise_max(e3_ + sm02[m], t3_ + c02[m]); \
      float p0_ = __builtin_amdgcn_exp2f(m0_.x);                       \
      float p1_ = __builtin_amdgcn_exp2f(m0_.y);                       \
      float p2_ = __builtin_amdgcn_exp2f(m1_.x);                       \
      float p3_ = __builtin_amdgcn_exp2f(m1_.y);                       \
      float p4_ = __builtin_amdgcn_exp2f(m2_.x);                       \
      float p5_ = __builtin_amdgcn_exp2f(m2_.y);                       \
      float p6_ = __builtin_amdgcn_exp2f(m3_.x);                       \
      float p7_ = __builtin_amdgcn_exp2f(m3_.y);                       \
      BF8 afu_;                                                        \
      afu_.u[0] = pkbf(p0_, p1_); afu_.u[1] = pkbf(p2_, p3_);          \
      afu_.u[2] = pkbf(p4_, p5_); afu_.u[3] = pkbf(p6_, p7_);          \
      acc[m][0] = __builtin_amdgcn_mfma_f32_16x16x32_bf16(afu_.v, B0_, acc[m][0], 0, 0, 0); \
      acc[m][1] = __builtin_amdgcn_mfma_f32_16x16x32_bf16(afu_.v, B1_, acc[m][1], 0, 0, 0); \
      acc[m][2] = __builtin_amdgcn_mfma_f32_16x16x32_bf16(afu_.v, B2_, acc[m][2], 0, 0, 0); \
      acc[m][3] = __builtin_amdgcn_mfma_f32_16x16x32_bf16(afu_.v, B3_, acc[m][3], 0, 0, 0); \
      accs[m]   = __builtin_amdgcn_mfma_f32_16x16x32_bf16(afu_.v, ones, accs[m], 0, 0, 0);  \
    }                                                                  \
  } while (0)

  bf16x8 A0, A1, A2, A3, B0, B1, B2, B3;
  float4 Ad0, Ad1, Bd0, Bd1;

  LOADF(A, 0);
#pragma unroll 1
  for (int jc2 = 0; jc2 < 31; ++jc2) {
    LOADF(B, 2 * jc2 + 1);
    FLASH_STEP(A0, A1, A2, A3, Ad0, Ad1);
    LOADF(A, 2 * jc2 + 2);
    FLASH_STEP(B0, B1, B2, B3, Bd0, Bd1);
  }
  LOADF(B, 63);
  FLASH_STEP(A0, A1, A2, A3, Ad0, Ad1);
  FLASH_STEP(B0, B1, B2, B3, Bd0, Bd1);

#undef LOADF
#undef FLASH_STEP

  float bb[4];
#pragma unroll
  for (int n = 0; n < 4; ++n) bb[n] = bias[n * 16 + l15];

  float* ob = out + ((size_t)bh * NN + it * 128 + w * 32) * HDIM;
#pragma unroll
  for (int m = 0; m < 2; ++m)
#pragma unroll
    for (int reg = 0; reg < 4; ++reg) {
      const float linv = 1.0f / accs[m][reg];   // rowsum, same lane & reg as acc
      const int r = m * 16 + lg * 4 + reg;
#pragma unroll
      for (int n = 0; n < 4; ++n)
        ob[(size_t)r * HDIM + n * 16 + l15] = fmaf(acc[m][n][reg], linv, bb[n]);
    }
}

extern "C" void kernel_launch(void* const* d_in, const int* in_sizes, int n_in,
                              void* d_out, int out_size, void* d_ws, size_t ws_size,
                              hipStream_t stream) {
  const float* h     = (const float*)d_in[0];   // [4,2048,256]
  const float* w     = (const float*)d_in[1];   // [8,256,64]
  const float* a_src = (const float*)d_in[2];   // [8,64,1]
  const float* a_dst = (const float*)d_in[3];   // [8,64,1]
  const float* bias  = (const float*)d_in[4];   // [64]
  float* out = (float*)d_out;                   // [4,8,2048,64]

  // ws layout (~8.75 MB)
  char* ws = (char*)d_ws;
  unsigned short* wt  = (unsigned short*)ws;                       // 256 KB
  unsigned short* h_t = (unsigned short*)(ws + 262144);            // 8 MB (V frag-major)
  float* src_s = (float*)(ws + 262144 + 8388608);                  // 256 KB
  float* dst_s = (float*)(ws + 262144 + 8388608 + 262144);         // 256 KB

  // bf16 copy of h lives in the FRONT of d_out (4 MB of 16 MB): written by
  // gat_hc, read only by gat_proj, then d_out is fully rewritten by gat_flash.
  unsigned short* hcv = (unsigned short*)d_out;

  hipLaunchKernelGGL(gat_wt,    dim3(512),     dim3(256), 0, stream, w, wt);
  hipLaunchKernelGGL(gat_hc,    dim3(1024),    dim3(256), 0, stream, h, hcv);
  hipLaunchKernelGGL(gat_proj,  dim3(8, 128),  dim3(256), 0, stream,
                     hcv, wt, a_src, a_dst, h_t, src_s, dst_s);
  hipLaunchKernelGGL(gat_flash, dim3(16, 32),  dim3(256), 0, stream,
                     src_s, dst_s, h_t, bias, out);
}

// Round 7
// 63.608 us; speedup vs baseline: 1.2198x; 1.2168x over previous
//
#include <hip/hip_runtime.h>
#include <cstdint>
#include <cstddef>

// GAT layer: B=4, H=8, N=2048, Din=256, O=64
// out[b,h,i,o] = sum_j softmax_j(leaky_relu(src[i]+dst[j])) * h_[b,h,j,o] + bias[o]
//
// Tricks:
//  - row max of logits = leaky(src_i + max_j dst_j) exactly (monotonicity).
//  - exp2 SEPARABILITY: p_ij = exp2(max(S+D-MI, .2S+.2D-MI)) =
//      max(u_i*E_j, v_i*F_j),  u=exp2(S-MI), v=exp2(.2S-MI),
//      E=exp2(D), F=exp2(.2D).  E/F built once per block in LDS ->
//      ZERO transcendentals in the inner loop. Both branches <= 1.
//  - p row-sums via MFMA vs all-ones B frag -> same lane/reg slot as PV acc.
//  - V stored FRAGMENT-MAJOR: h_t[bh][j>>3][o][j&7] -> B-frag load = 4
//    contiguous 256B runs. 2-deep register double-buffer in flash.
//  - h converted to bf16 once (front of d_out, rewritten later by flash).
//  - f32->bf16 pack: +0x8000 half-up + v_perm (R3's v_cvt_pk asm was buggy).

#define HEADS 8
#define DIN   256
#define HDIM  64
#define NN    2048

typedef __attribute__((ext_vector_type(8))) short bf16x8;
typedef __attribute__((ext_vector_type(4))) float f32x4;
typedef __attribute__((ext_vector_type(2))) float f32x2;

union BF8 { bf16x8 v; unsigned u[4]; };

__device__ __forceinline__ unsigned pkbf(float a, float b) {
  // returns (bf16(b)<<16) | bf16(a), round-half-up
  union { float f; unsigned u; } ua, ub; ua.f = a; ub.f = b;
  return __builtin_amdgcn_perm(ub.u + 0x8000u, ua.u + 0x8000u, 0x07060302u);
}

__device__ __forceinline__ unsigned short f2bf(float f) {
  union { float f; unsigned u; } v; v.f = f;
  unsigned r = v.u + 0x7FFFu + ((v.u >> 16) & 1u);   // RNE
  return (unsigned short)(r >> 16);
}

// ---------------- k0a: w [H][K][O] f32 -> wt [H][O][K] bf16 ---------------
__global__ __launch_bounds__(256) void gat_wt(const float* __restrict__ w,
                                              unsigned short* __restrict__ wt) {
  const int idx = blockIdx.x * 256 + threadIdx.x;   // over 8*256*64 = 131072
  const int o  = idx & 63;
  const int k  = (idx >> 6) & 255;
  const int hd = idx >> 14;
  wt[(hd * HDIM + o) * DIN + k] = f2bf(w[idx]);
}

// ---------------- k0b: h f32 -> bf16 (once, not 8x per head) --------------
__global__ __launch_bounds__(256) void gat_hc(const float* __restrict__ h,
                                              unsigned short* __restrict__ hc) {
  const int idx = blockIdx.x * 256 + threadIdx.x;   // 262144 threads x 8 elems
  const float* p = h + (size_t)idx * 8;
  float4 x0 = ((const float4*)p)[0];
  float4 x1 = ((const float4*)p)[1];
  uint4 o;
  o.x = pkbf(x0.x, x0.y); o.y = pkbf(x0.z, x0.w);
  o.z = pkbf(x1.x, x1.y); o.w = pkbf(x1.z, x1.w);
  *(uint4*)(hc + (size_t)idx * 8) = o;
}

// ---------------- k1: projection + fused src/dst logit vectors ------------
// grid (HEADS, 64): head = bx, 128-row tile of B*N=8192 = by  (R4 shape)
// writes V fragment-major: h_t[bh][g = j>>3][o][j&7]  (g stride 512 elems)
__global__ __launch_bounds__(256) void gat_proj(const unsigned short* __restrict__ hc,
                                                const unsigned short* __restrict__ wt,
                                                const float* __restrict__ a_src,
                                                const float* __restrict__ a_dst,
                                                unsigned short* __restrict__ h_t,
                                                float* __restrict__ src_s,
                                                float* __restrict__ dst_s) {
  const int head = blockIdx.x;
  const int rt   = blockIdx.y;
  const int tid  = threadIdx.x;
  const int w    = tid >> 6;
  const int lane = tid & 63;
  const int l15  = lane & 15, lg = lane >> 4;

  const int rowg = rt * 128 + w * 32;                 // global row in [0,8192)
  const unsigned short* hb = hc + (size_t)rowg * DIN;
  const unsigned short* wb = wt + head * (HDIM * DIN);

  f32x4 acc[2][4] = {};
#pragma unroll
  for (int kk = 0; kk < 8; ++kk) {
    const int k0 = kk * 32 + lg * 8;
    bf16x8 af[2];
#pragma unroll
    for (int m = 0; m < 2; ++m)
      af[m] = *(const bf16x8*)(hb + (size_t)(m * 16 + l15) * DIN + k0);
    bf16x8 bfr[4];
#pragma unroll
    for (int n = 0; n < 4; ++n)
      bfr[n] = *(const bf16x8*)(wb + (size_t)(n * 16 + l15) * DIN + k0);
#pragma unroll
    for (int m = 0; m < 2; ++m)
#pragma unroll
      for (int n = 0; n < 4; ++n)
        acc[m][n] = __builtin_amdgcn_mfma_f32_16x16x32_bf16(af[m], bfr[n], acc[m][n], 0, 0, 0);
  }

  // fragment-major store: C regs are 4 consecutive rows(j), same col(o)
  const int b   = (rt * 128) >> 11;
  const int nl0 = ((rt * 128) & 2047) + w * 32;       // node index within batch b
  const int bh  = b * HEADS + head;
  unsigned short* hb_t = h_t + (size_t)bh * (256 * 512);
#pragma unroll
  for (int m = 0; m < 2; ++m)
#pragma unroll
    for (int n = 0; n < 4; ++n) {
      uint2 pk;
      pk.x = pkbf(acc[m][n][0], acc[m][n][1]);
      pk.y = pkbf(acc[m][n][2], acc[m][n][3]);
      const int j0 = nl0 + m * 16 + lg * 4;           // 4 consecutive j
      const int o  = n * 16 + l15;
      *(uint2*)(hb_t + (size_t)(j0 >> 3) * 512 + o * 8 + (j0 & 7)) = pk;
    }

  // fused src/dst: src[node] = sum_o h_[node][o]*a_src[o]  (f32 acc, pre-scaled)
  const float LOG2E = 1.4426950408889634f;
  float as4[4], ad4[4];
#pragma unroll
  for (int n = 0; n < 4; ++n) {
    as4[n] = a_src[head * HDIM + n * 16 + l15];
    ad4[n] = a_dst[head * HDIM + n * 16 + l15];
  }
#pragma unroll
  for (int m = 0; m < 2; ++m)
#pragma unroll
    for (int reg = 0; reg < 4; ++reg) {
      float ps = 0.f, pd = 0.f;
#pragma unroll
      for (int n = 0; n < 4; ++n) {
        float c = acc[m][n][reg];
        ps = fmaf(c, as4[n], ps);
        pd = fmaf(c, ad4[n], pd);
      }
#pragma unroll
      for (int off = 1; off <= 8; off <<= 1) {
        ps += __shfl_xor(ps, off);
        pd += __shfl_xor(pd, off);
      }
      if (l15 == 0) {
        const int nl = nl0 + m * 16 + lg * 4 + reg;
        src_s[(size_t)bh * NN + nl] = ps * LOG2E;
        dst_s[(size_t)bh * NN + nl] = pd * LOG2E;
      }
    }
}

// ---------------- k2: flash GAT attention ---------------------------------
// grid (16, 32): i-tile(128 rows) = bx, bh = by; 4 waves x 32 rows (2 m-tiles)
__global__ __launch_bounds__(256) void gat_flash(const float* __restrict__ src_s,
                                                 const float* __restrict__ dst_s,
                                                 const unsigned short* __restrict__ h_t,
                                                 const float* __restrict__ bias,
                                                 float* __restrict__ out) {
  const int it  = blockIdx.x;
  const int bh  = blockIdx.y;
  const int tid = threadIdx.x;
  const int w   = tid >> 6;
  const int lane = tid & 63;
  const int l15 = lane & 15, lg = lane >> 4;

  __shared__ float Elds[NN];
  __shared__ float Flds[NN];
  __shared__ float red[4];

  const float* dstp = dst_s + (size_t)bh * NN;

  // prologue: global dst max for this (b,h) + E/F tables into LDS
  float dm = -1e30f;
#pragma unroll
  for (int t = 0; t < NN / 256; ++t) {
    const int j = tid + t * 256;
    float d = dstp[j];
    dm = fmaxf(dm, d);
    Elds[j] = __builtin_amdgcn_exp2f(d);
    Flds[j] = __builtin_amdgcn_exp2f(0.2f * d);
  }
#pragma unroll
  for (int off = 32; off >= 1; off >>= 1) dm = fmaxf(dm, __shfl_xor(dm, off));
  if (lane == 0) red[w] = dm;
  __syncthreads();                                    // also fences Elds/Flds
  dm = fmaxf(fmaxf(red[0], red[1]), fmaxf(red[2], red[3]));

  // per-lane row state: A-frag row = l15 within each 16-row m-tile
  const float* srcp = src_s + (size_t)bh * NN + it * 128 + w * 32;
  f32x2 u2[2], v2[2];
#pragma unroll
  for (int m = 0; m < 2; ++m) {
    float sv   = srcp[m * 16 + l15];
    float smax = sv + dm;
    float mi   = fmaxf(smax, 0.2f * smax);   // exact row max (log2 domain)
    float u    = __builtin_amdgcn_exp2f(sv - mi);          // pos branch scale
    float v    = __builtin_amdgcn_exp2f(fmaf(0.2f, sv, -mi)); // neg branch scale
    u2[m] = (f32x2){u, u};
    v2[m] = (f32x2){v, v};
  }

  f32x4 acc[2][4] = {};
  f32x4 accs[2]   = {};
  BF8 onesU; onesU.u[0] = onesU.u[1] = onesU.u[2] = onesU.u[3] = 0x3F803F80u;
  const bf16x8 ones = onesU.v;

  // fragment-major base for this lane: group (jc*4+lg), col (n*16+l15)
  const unsigned short* fb = h_t + (size_t)bh * (256 * 512) + lg * 512 + l15 * 8;

#define LOADF(P, jc) do {                                              \
    const unsigned short* fp_ = fb + (size_t)(jc) * 2048;              \
    P##0 = *(const bf16x8*)(fp_);                                      \
    P##1 = *(const bf16x8*)(fp_ + 128);                                \
    P##2 = *(const bf16x8*)(fp_ + 256);                                \
    P##3 = *(const bf16x8*)(fp_ + 384);                                \
    P##e0 = *(const f32x4*)(&Elds[(jc) * 32 + lg * 8]);                \
    P##e1 = *(const f32x4*)(&Elds[(jc) * 32 + lg * 8 + 4]);            \
    P##f0 = *(const f32x4*)(&Flds[(jc) * 32 + lg * 8]);                \
    P##f1 = *(const f32x4*)(&Flds[(jc) * 32 + lg * 8 + 4]);            \
  } while (0)

#define FLASH_STEP(B0_, B1_, B2_, B3_, E0_, E1_, F0_, F1_) do {        \
    f32x2 e0_ = {E0_[0], E0_[1]}, e1_ = {E0_[2], E0_[3]};              \
    f32x2 e2_ = {E1_[0], E1_[1]}, e3_ = {E1_[2], E1_[3]};              \
    f32x2 f0_ = {F0_[0], F0_[1]}, f1_ = {F0_[2], F0_[3]};              \
    f32x2 f2_ = {F1_[0], F1_[1]}, f3_ = {F1_[2], F1_[3]};              \
    _Pragma("unroll") for (int m = 0; m < 2; ++m) {                    \
      f32x2 m0_ = __builtin_elementwise_max(u2[m] * e0_, v2[m] * f0_); \
      f32x2 m1_ = __builtin_elementwise_max(u2[m] * e1_, v2[m] * f1_); \
      f32x2 m2_ = __builtin_elementwise_max(u2[m] * e2_, v2[m] * f2_); \
      f32x2 m3_ = __builtin_elementwise_max(u2[m] * e3_, v2[m] * f3_); \
      BF8 afu_;                                                        \
      afu_.u[0] = pkbf(m0_.x, m0_.y); afu_.u[1] = pkbf(m1_.x, m1_.y);  \
      afu_.u[2] = pkbf(m2_.x, m2_.y); afu_.u[3] = pkbf(m3_.x, m3_.y);  \
      acc[m][0] = __builtin_amdgcn_mfma_f32_16x16x32_bf16(afu_.v, B0_, acc[m][0], 0, 0, 0); \
      acc[m][1] = __builtin_amdgcn_mfma_f32_16x16x32_bf16(afu_.v, B1_, acc[m][1], 0, 0, 0); \
      acc[m][2] = __builtin_amdgcn_mfma_f32_16x16x32_bf16(afu_.v, B2_, acc[m][2], 0, 0, 0); \
      acc[m][3] = __builtin_amdgcn_mfma_f32_16x16x32_bf16(afu_.v, B3_, acc[m][3], 0, 0, 0); \
      accs[m]   = __builtin_amdgcn_mfma_f32_16x16x32_bf16(afu_.v, ones, accs[m], 0, 0, 0);  \
    }                                                                  \
  } while (0)

  bf16x8 A0, A1, A2, A3, B0, B1, B2, B3;
  f32x4 Ae0, Ae1, Af0, Af1, Be0, Be1, Bf0, Bf1;

  LOADF(A, 0);
#pragma unroll 1
  for (int jc2 = 0; jc2 < 31; ++jc2) {
    LOADF(B, 2 * jc2 + 1);
    FLASH_STEP(A0, A1, A2, A3, Ae0, Ae1, Af0, Af1);
    LOADF(A, 2 * jc2 + 2);
    FLASH_STEP(B0, B1, B2, B3, Be0, Be1, Bf0, Bf1);
  }
  LOADF(B, 63);
  FLASH_STEP(A0, A1, A2, A3, Ae0, Ae1, Af0, Af1);
  FLASH_STEP(B0, B1, B2, B3, Be0, Be1, Bf0, Bf1);

#undef LOADF
#undef FLASH_STEP

  float bb[4];
#pragma unroll
  for (int n = 0; n < 4; ++n) bb[n] = bias[n * 16 + l15];

  float* ob = out + ((size_t)bh * NN + it * 128 + w * 32) * HDIM;
#pragma unroll
  for (int m = 0; m < 2; ++m)
#pragma unroll
    for (int reg = 0; reg < 4; ++reg) {
      const float linv = 1.0f / accs[m][reg];   // rowsum, same lane & reg as acc
      const int r = m * 16 + lg * 4 + reg;
#pragma unroll
      for (int n = 0; n < 4; ++n)
        ob[(size_t)r * HDIM + n * 16 + l15] = fmaf(acc[m][n][reg], linv, bb[n]);
    }
}

extern "C" void kernel_launch(void* const* d_in, const int* in_sizes, int n_in,
                              void* d_out, int out_size, void* d_ws, size_t ws_size,
                              hipStream_t stream) {
  const float* h     = (const float*)d_in[0];   // [4,2048,256]
  const float* w     = (const float*)d_in[1];   // [8,256,64]
  const float* a_src = (const float*)d_in[2];   // [8,64,1]
  const float* a_dst = (const float*)d_in[3];   // [8,64,1]
  const float* bias  = (const float*)d_in[4];   // [64]
  float* out = (float*)d_out;                   // [4,8,2048,64]

  // ws layout (~8.75 MB)
  char* ws = (char*)d_ws;
  unsigned short* wt  = (unsigned short*)ws;                       // 256 KB
  unsigned short* h_t = (unsigned short*)(ws + 262144);            // 8 MB (V frag-major)
  float* src_s = (float*)(ws + 262144 + 8388608);                  // 256 KB
  float* dst_s = (float*)(ws + 262144 + 8388608 + 262144);         // 256 KB

  // bf16 copy of h lives in the FRONT of d_out (4 MB of 16 MB): written by
  // gat_hc, read only by gat_proj, then d_out is fully rewritten by gat_flash.
  unsigned short* hcv = (unsigned short*)d_out;

  hipLaunchKernelGGL(gat_wt,    dim3(512),    dim3(256), 0, stream, w, wt);
  hipLaunchKernelGGL(gat_hc,    dim3(1024),   dim3(256), 0, stream, h, hcv);
  hipLaunchKernelGGL(gat_proj,  dim3(8, 64),  dim3(256), 0, stream,
                     hcv, wt, a_src, a_dst, h_t, src_s, dst_s);
  hipLaunchKernelGGL(gat_flash, dim3(16, 32), dim3(256), 0, stream,
                     src_s, dst_s, h_t, bias, out);
}

// Round 9
// 60.496 us; speedup vs baseline: 1.2825x; 1.0514x over previous
//
#include <hip/hip_runtime.h>
#include <cstdint>
#include <cstddef>

// GAT layer: B=4, H=8, N=2048, Din=256, O=64
// out[b,h,i,o] = sum_j softmax_j(leaky_relu(src[i]+dst[j])) * h_[b,h,j,o] + bias[o]
//
// Tricks:
//  - row max of logits = leaky(src_i + max_j dst_j) exactly (monotonicity).
//  - exp2 SEPARABILITY, dm-shifted so every factor is provably <= 1 (f16-safe):
//      p_ij = max(u_i*E_j, v_i*F_j),  E=exp2(D-dm), F=exp2(.2(D-dm)),
//      u=exp2(smax-MI), v=exp2(.2*smax-MI), smax=S+dm, MI=max(smax,.2*smax).
//    E/F built once per block in LDS (f16) -> zero transcendentals inner loop.
//  - ALL intermediates f16: packed f16 mul/max output IS the MFMA A-frag
//    (no pack step); V/w/h-copy f16; mfma_f32_16x16x32_f16; f32->f16 pack via
//    __builtin_amdgcn_cvt_pkrtz (bitcast its __fp16x2 result to our f16x2 —
//    R8 fixes R7's type-mismatch compile error).
//  - p row-sums via MFMA vs all-ones B frag -> same lane/reg slot as PV acc.
//  - V stored FRAGMENT-MAJOR: h_t[bh][j>>3][o][j&7] -> B-frag load = 4
//    contiguous 256B runs. 2-deep register double-buffer in flash.

#define HEADS 8
#define DIN   256
#define HDIM  64
#define NN    2048

typedef __attribute__((ext_vector_type(8))) _Float16 f16x8;
typedef __attribute__((ext_vector_type(2))) _Float16 f16x2;
typedef __attribute__((ext_vector_type(2))) __fp16   fp16x2;
typedef __attribute__((ext_vector_type(4))) float f32x4;

union H8 { f16x8 v; f16x2 p[4]; unsigned u[4]; };
union F2U { f16x2 h; fp16x2 q; unsigned u; };

__device__ __forceinline__ f16x2 pkrtz(float a, float b) {
  F2U t; t.q = __builtin_amdgcn_cvt_pkrtz(a, b);   // v_cvt_pkrtz_f16_f32
  return t.h;
}
__device__ __forceinline__ unsigned pkrtz_u(float a, float b) {
  F2U t; t.q = __builtin_amdgcn_cvt_pkrtz(a, b);
  return t.u;
}

// ---------------- k0a: w [H][K][O] f32 -> wt [H][O][K] f16 ----------------
__global__ __launch_bounds__(256) void gat_wt(const float* __restrict__ w,
                                              _Float16* __restrict__ wt) {
  const int idx = blockIdx.x * 256 + threadIdx.x;   // over 8*256*64 = 131072
  const int o  = idx & 63;
  const int k  = (idx >> 6) & 255;
  const int hd = idx >> 14;
  wt[(hd * HDIM + o) * DIN + k] = (_Float16)w[idx];
}

// ---------------- k0b: h f32 -> f16 (once, not 8x per head) ---------------
__global__ __launch_bounds__(256) void gat_hc(const float* __restrict__ h,
                                              _Float16* __restrict__ hc) {
  const int idx = blockIdx.x * 256 + threadIdx.x;   // 262144 threads x 8 elems
  const float* p = h + (size_t)idx * 8;
  float4 x0 = ((const float4*)p)[0];
  float4 x1 = ((const float4*)p)[1];
  H8 o;
  o.p[0] = pkrtz(x0.x, x0.y); o.p[1] = pkrtz(x0.z, x0.w);
  o.p[2] = pkrtz(x1.x, x1.y); o.p[3] = pkrtz(x1.z, x1.w);
  *(f16x8*)(hc + (size_t)idx * 8) = o.v;
}

// ---------------- k1: projection + fused src/dst logit vectors ------------
// grid (HEADS, 64): head = bx, 128-row tile of B*N=8192 = by
// writes V fragment-major: h_t[bh][g = j>>3][o][j&7]  (g stride 512 elems)
__global__ __launch_bounds__(256) void gat_proj(const _Float16* __restrict__ hc,
                                                const _Float16* __restrict__ wt,
                                                const float* __restrict__ a_src,
                                                const float* __restrict__ a_dst,
                                                _Float16* __restrict__ h_t,
                                                float* __restrict__ src_s,
                                                float* __restrict__ dst_s) {
  const int head = blockIdx.x;
  const int rt   = blockIdx.y;
  const int tid  = threadIdx.x;
  const int w    = tid >> 6;
  const int lane = tid & 63;
  const int l15  = lane & 15, lg = lane >> 4;

  const int rowg = rt * 128 + w * 32;                 // global row in [0,8192)
  const _Float16* hb = hc + (size_t)rowg * DIN;
  const _Float16* wb = wt + head * (HDIM * DIN);

  f32x4 acc[2][4] = {};
#pragma unroll
  for (int kk = 0; kk < 8; ++kk) {
    const int k0 = kk * 32 + lg * 8;
    f16x8 af[2];
#pragma unroll
    for (int m = 0; m < 2; ++m)
      af[m] = *(const f16x8*)(hb + (size_t)(m * 16 + l15) * DIN + k0);
    f16x8 bfr[4];
#pragma unroll
    for (int n = 0; n < 4; ++n)
      bfr[n] = *(const f16x8*)(wb + (size_t)(n * 16 + l15) * DIN + k0);
#pragma unroll
    for (int m = 0; m < 2; ++m)
#pragma unroll
      for (int n = 0; n < 4; ++n)
        acc[m][n] = __builtin_amdgcn_mfma_f32_16x16x32_f16(af[m], bfr[n], acc[m][n], 0, 0, 0);
  }

  // fragment-major store: C regs are 4 consecutive rows(j), same col(o)
  const int b   = (rt * 128) >> 11;
  const int nl0 = ((rt * 128) & 2047) + w * 32;       // node index within batch b
  const int bh  = b * HEADS + head;
  _Float16* hb_t = h_t + (size_t)bh * (256 * 512);
#pragma unroll
  for (int m = 0; m < 2; ++m)
#pragma unroll
    for (int n = 0; n < 4; ++n) {
      uint2 pk;
      pk.x = pkrtz_u(acc[m][n][0], acc[m][n][1]);
      pk.y = pkrtz_u(acc[m][n][2], acc[m][n][3]);
      const int j0 = nl0 + m * 16 + lg * 4;           // 4 consecutive j
      const int o  = n * 16 + l15;
      *(uint2*)(hb_t + (size_t)(j0 >> 3) * 512 + o * 8 + (j0 & 7)) = pk;
    }

  // fused src/dst: src[node] = sum_o h_[node][o]*a_src[o]  (f32 acc, pre-scaled)
  const float LOG2E = 1.4426950408889634f;
  float as4[4], ad4[4];
#pragma unroll
  for (int n = 0; n < 4; ++n) {
    as4[n] = a_src[head * HDIM + n * 16 + l15];
    ad4[n] = a_dst[head * HDIM + n * 16 + l15];
  }
#pragma unroll
  for (int m = 0; m < 2; ++m)
#pragma unroll
    for (int reg = 0; reg < 4; ++reg) {
      float ps = 0.f, pd = 0.f;
#pragma unroll
      for (int n = 0; n < 4; ++n) {
        float c = acc[m][n][reg];
        ps = fmaf(c, as4[n], ps);
        pd = fmaf(c, ad4[n], pd);
      }
#pragma unroll
      for (int off = 1; off <= 8; off <<= 1) {
        ps += __shfl_xor(ps, off);
        pd += __shfl_xor(pd, off);
      }
      if (l15 == 0) {
        const int nl = nl0 + m * 16 + lg * 4 + reg;
        src_s[(size_t)bh * NN + nl] = ps * LOG2E;
        dst_s[(size_t)bh * NN + nl] = pd * LOG2E;
      }
    }
}

// ---------------- k2: flash GAT attention ---------------------------------
// grid (16, 32): i-tile(128 rows) = bx, bh = by; 4 waves x 32 rows (2 m-tiles)
__global__ __launch_bounds__(256) void gat_flash(const float* __restrict__ src_s,
                                                 const float* __restrict__ dst_s,
                                                 const _Float16* __restrict__ h_t,
                                                 const float* __restrict__ bias,
                                                 float* __restrict__ out) {
  const int it  = blockIdx.x;
  const int bh  = blockIdx.y;
  const int tid = threadIdx.x;
  const int w   = tid >> 6;
  const int lane = tid & 63;
  const int l15 = lane & 15, lg = lane >> 4;

  __shared__ _Float16 Ef[NN];    // 4 KB
  __shared__ _Float16 Ff[NN];    // 4 KB
  __shared__ float red[4];

  const float* dstp = dst_s + (size_t)bh * NN;

  // pass 1: this thread's 8 dst values + global max dm for this (b,h)
  float d[8];
  {
    float4 q0 = *(const float4*)(dstp + tid * 8);
    float4 q1 = *(const float4*)(dstp + tid * 8 + 4);
    d[0]=q0.x; d[1]=q0.y; d[2]=q0.z; d[3]=q0.w;
    d[4]=q1.x; d[5]=q1.y; d[6]=q1.z; d[7]=q1.w;
  }
  float dm = fmaxf(fmaxf(fmaxf(d[0],d[1]),fmaxf(d[2],d[3])),
                   fmaxf(fmaxf(d[4],d[5]),fmaxf(d[6],d[7])));
#pragma unroll
  for (int off = 32; off >= 1; off >>= 1) dm = fmaxf(dm, __shfl_xor(dm, off));
  if (lane == 0) red[w] = dm;
  __syncthreads();
  dm = fmaxf(fmaxf(red[0], red[1]), fmaxf(red[2], red[3]));

  // pass 2: E/F tables (f16, all <= 1 by dm shift)
  {
    H8 e8, f8;
#pragma unroll
    for (int k = 0; k < 4; ++k) {
      float a0 = d[2*k]   - dm;
      float a1 = d[2*k+1] - dm;
      e8.p[k] = pkrtz(__builtin_amdgcn_exp2f(a0), __builtin_amdgcn_exp2f(a1));
      f8.p[k] = pkrtz(__builtin_amdgcn_exp2f(0.2f * a0),
                      __builtin_amdgcn_exp2f(0.2f * a1));
    }
    *(f16x8*)(&Ef[tid * 8]) = e8.v;
    *(f16x8*)(&Ff[tid * 8]) = f8.v;
  }
  __syncthreads();

  // per-lane row state: A-frag row = l15 within each 16-row m-tile
  const float* srcp = src_s + (size_t)bh * NN + it * 128 + w * 32;
  f16x2 u2[2], v2[2];
#pragma unroll
  for (int m = 0; m < 2; ++m) {
    float sv   = srcp[m * 16 + l15];
    float smax = sv + dm;
    float mi   = fmaxf(smax, 0.2f * smax);   // exact row max (log2 domain)
    float u    = __builtin_amdgcn_exp2f(smax - mi);          // <= 1
    float v    = __builtin_amdgcn_exp2f(fmaf(0.2f, smax, -mi)); // <= 1
    u2[m] = pkrtz(u, u);
    v2[m] = pkrtz(v, v);
  }

  f32x4 acc[2][4] = {};
  f32x4 accs[2]   = {};
  H8 onesU; onesU.u[0] = onesU.u[1] = onesU.u[2] = onesU.u[3] = 0x3C003C00u;
  const f16x8 ones = onesU.v;

  // fragment-major base for this lane: group (jc*4+lg), col (n*16+l15)
  const _Float16* fb = h_t + (size_t)bh * (256 * 512) + lg * 512 + l15 * 8;

#define LOADF(P, jc) do {                                              \
    const _Float16* fp_ = fb + (size_t)(jc) * 2048;                    \
    P##0 = *(const f16x8*)(fp_);                                       \
    P##1 = *(const f16x8*)(fp_ + 128);                                 \
    P##2 = *(const f16x8*)(fp_ + 256);                                 \
    P##3 = *(const f16x8*)(fp_ + 384);                                 \
    P##e = *(const f16x8*)(&Ef[(jc) * 32 + lg * 8]);                   \
    P##f = *(const f16x8*)(&Ff[(jc) * 32 + lg * 8]);                   \
  } while (0)

#define FLASH_STEP(B0_, B1_, B2_, B3_, E_, F_) do {                    \
    H8 eu_, fu_; eu_.v = E_; fu_.v = F_;                               \
    _Pragma("unroll") for (int m = 0; m < 2; ++m) {                    \
      H8 af_;                                                          \
      af_.p[0] = __builtin_elementwise_max(u2[m] * eu_.p[0], v2[m] * fu_.p[0]); \
      af_.p[1] = __builtin_elementwise_max(u2[m] * eu_.p[1], v2[m] * fu_.p[1]); \
      af_.p[2] = __builtin_elementwise_max(u2[m] * eu_.p[2], v2[m] * fu_.p[2]); \
      af_.p[3] = __builtin_elementwise_max(u2[m] * eu_.p[3], v2[m] * fu_.p[3]); \
      acc[m][0] = __builtin_amdgcn_mfma_f32_16x16x32_f16(af_.v, B0_, acc[m][0], 0, 0, 0); \
      acc[m][1] = __builtin_amdgcn_mfma_f32_16x16x32_f16(af_.v, B1_, acc[m][1], 0, 0, 0); \
      acc[m][2] = __builtin_amdgcn_mfma_f32_16x16x32_f16(af_.v, B2_, acc[m][2], 0, 0, 0); \
      acc[m][3] = __builtin_amdgcn_mfma_f32_16x16x32_f16(af_.v, B3_, acc[m][3], 0, 0, 0); \
      accs[m]   = __builtin_amdgcn_mfma_f32_16x16x32_f16(af_.v, ones, accs[m], 0, 0, 0);  \
    }                                                                  \
  } while (0)

  f16x8 A0, A1, A2, A3, B0, B1, B2, B3;
  f16x8 Ae, Af, Be, Bf;

  LOADF(A, 0);
#pragma unroll 1
  for (int jc2 = 0; jc2 < 31; ++jc2) {
    LOADF(B, 2 * jc2 + 1);
    FLASH_STEP(A0, A1, A2, A3, Ae, Af);
    LOADF(A, 2 * jc2 + 2);
    FLASH_STEP(B0, B1, B2, B3, Be, Bf);
  }
  LOADF(B, 63);
  FLASH_STEP(A0, A1, A2, A3, Ae, Af);
  FLASH_STEP(B0, B1, B2, B3, Be, Bf);

#undef LOADF
#undef FLASH_STEP

  float bb[4];
#pragma unroll
  for (int n = 0; n < 4; ++n) bb[n] = bias[n * 16 + l15];

  float* ob = out + ((size_t)bh * NN + it * 128 + w * 32) * HDIM;
#pragma unroll
  for (int m = 0; m < 2; ++m)
#pragma unroll
    for (int reg = 0; reg < 4; ++reg) {
      const float linv = 1.0f / accs[m][reg];   // rowsum, same lane & reg as acc
      const int r = m * 16 + lg * 4 + reg;
#pragma unroll
      for (int n = 0; n < 4; ++n)
        ob[(size_t)r * HDIM + n * 16 + l15] = fmaf(acc[m][n][reg], linv, bb[n]);
    }
}

extern "C" void kernel_launch(void* const* d_in, const int* in_sizes, int n_in,
                              void* d_out, int out_size, void* d_ws, size_t ws_size,
                              hipStream_t stream) {
  const float* h     = (const float*)d_in[0];   // [4,2048,256]
  const float* w     = (const float*)d_in[1];   // [8,256,64]
  const float* a_src = (const float*)d_in[2];   // [8,64,1]
  const float* a_dst = (const float*)d_in[3];   // [8,64,1]
  const float* bias  = (const float*)d_in[4];   // [64]
  float* out = (float*)d_out;                   // [4,8,2048,64]

  // ws layout (~8.75 MB)
  char* ws = (char*)d_ws;
  _Float16* wt  = (_Float16*)ws;                                   // 256 KB
  _Float16* h_t = (_Float16*)(ws + 262144);                        // 8 MB (V frag-major)
  float* src_s = (float*)(ws + 262144 + 8388608);                  // 256 KB
  float* dst_s = (float*)(ws + 262144 + 8388608 + 262144);         // 256 KB

  // f16 copy of h lives in the FRONT of d_out (4 MB of 16 MB): written by
  // gat_hc, read only by gat_proj, then d_out is fully rewritten by gat_flash.
  _Float16* hcv = (_Float16*)d_out;

  hipLaunchKernelGGL(gat_wt,    dim3(512),    dim3(256), 0, stream, w, wt);
  hipLaunchKernelGGL(gat_hc,    dim3(1024),   dim3(256), 0, stream, h, hcv);
  hipLaunchKernelGGL(gat_proj,  dim3(8, 64),  dim3(256), 0, stream,
                     hcv, wt, a_src, a_dst, h_t, src_s, dst_s);
  hipLaunchKernelGGL(gat_flash, dim3(16, 32), dim3(256), 0, stream,
                     src_s, dst_s, h_t, bias, out);
}